// Round 1
// baseline (335.614 us; speedup 1.0000x reference)
//
#include <hip/hip_runtime.h>
#include <stdint.h>
#include <stddef.h>

// ---------------------------------------------------------------------------
// B=4, N=2048, D=768, H=12, HD=64. BN=8192.
// I/O fp32; internal bf16 MFMA + fp32 accum.
// qkv hidden [8192][2304] bf16 (Q 0..767 | K 768..1535 | V 1536..2303).
// V also materialized transposed: VT[(b*12+h)*64+d][2048 j] (aliases xb).
// Attention overwrites the Q region in place with merged-head output.
// attn v7: wave-independent 32-q-per-wave flash attention, swapped QK^T with
// 32x32x16 MFMAs, P kept in registers via v_cvt_pk_bf16_f32 + permlane32_swap
// (no P LDS round-trip, no main-loop barriers, no bank conflicts).
// ---------------------------------------------------------------------------

typedef __bf16 bf16x8 __attribute__((ext_vector_type(8)));
typedef float  f32x4  __attribute__((ext_vector_type(4)));
typedef float  f32x16 __attribute__((ext_vector_type(16)));
typedef unsigned int u32x2 __attribute__((ext_vector_type(2)));

__device__ __forceinline__ float bf2f(unsigned short u){
  union { unsigned int i; float f; } x; x.i = ((unsigned int)u) << 16; return x.f;
}
// round-half-up bf16
__device__ __forceinline__ unsigned short fast2bf(float f){
  union { float f; unsigned int i; } x; x.f = f;
  return (unsigned short)((x.i + 0x8000u) >> 16);
}
__device__ __forceinline__ unsigned int fbits(float f){
  union { float f; unsigned int i; } x; x.f = f; return x.i;
}
// pack two fp32 -> two bf16 (round-half-up) in one dword: 2 adds + 1 v_perm
__device__ __forceinline__ unsigned int pk2bf(float lo, float hi){
  unsigned int a = fbits(lo) + 0x8000u;
  unsigned int b = fbits(hi) + 0x8000u;
  return __builtin_amdgcn_perm(b, a, 0x07060302u);  // {b[31:16], a[31:16]}
}
// single-instruction packed fp32->bf16 pair (RNE)
__device__ __forceinline__ unsigned int cvtpk_bf16(float lo, float hi){
  unsigned int r;
  asm("v_cvt_pk_bf16_f32 %0, %1, %2" : "=v"(r) : "v"(lo), "v"(hi));
  return r;
}
// v_permlane32_swap_b32: a' = {a.lo32lanes, b.lo32lanes}, b' = {a.hi, b.hi}
__device__ __forceinline__ void plswap32(unsigned int &a, unsigned int &b){
#if __has_builtin(__builtin_amdgcn_permlane32_swap)
  u32x2 r = __builtin_amdgcn_permlane32_swap(a, b, false, false);
  a = r.x; b = r.y;
#else
  asm volatile("v_permlane32_swap_b32 %0, %1" : "+v"(a), "+v"(b));
#endif
}

#if __has_builtin(__builtin_amdgcn_exp2f)
  #define EXP2F(x) __builtin_amdgcn_exp2f(x)
#else
  #define EXP2F(x) exp2f(x)
#endif

// async global->LDS, 16B per lane; LDS dest = wave-uniform base + lane*16.
#define GLD16(gp, lp) __builtin_amdgcn_global_load_lds( \
  (__attribute__((address_space(1))) void*)(uintptr_t)(gp), \
  (__attribute__((address_space(3))) void*)(unsigned int)(uintptr_t)(lp), 16, 0, 0)

// ---------------------------------------------------------------------------
__global__ void f32_to_bf16(const float* __restrict__ in,
                            unsigned short* __restrict__ out, int n){
  int i = (blockIdx.x * 256 + threadIdx.x) * 4;
  if(i < n){
    float4 v = *(const float4*)(in + i);
    ushort4 o;
    o.x = fast2bf(v.x); o.y = fast2bf(v.y); o.z = fast2bf(v.z); o.w = fast2bf(v.w);
    *(ushort4*)(out + i) = o;
  }
}

// ---------------------------------------------------------------------------
__global__ void transpose_f32_bf16(const float* __restrict__ W,
                                   unsigned short* __restrict__ Wt, int K, int N){
  __shared__ float tile[32][33];
  int n0 = blockIdx.x * 32, k0 = blockIdx.y * 32;
  int tx = threadIdx.x, ty = threadIdx.y;   // (32,8)
  for(int i = ty; i < 32; i += 8) tile[i][tx] = W[(size_t)(k0 + i) * N + (n0 + tx)];
  __syncthreads();
  for(int i = ty; i < 32; i += 8) Wt[(size_t)(n0 + i) * K + (k0 + tx)] = fast2bf(tile[tx][i]);
}

// ---------------------------------------------------------------------------
// V transpose: VT[(b*12+h)*64 + d][j] = qkv[b*2048+j][1536 + h*64 + d]
// ---------------------------------------------------------------------------
__global__ __launch_bounds__(256) void transpose_v(const unsigned short* __restrict__ qkv,
                                                   unsigned short* __restrict__ VT){
  __shared__ __align__(16) unsigned short Ts[64*72];
  const int t  = threadIdx.x;
  const int jt = blockIdx.x;        // 0..31
  const int bh = blockIdx.y;        // 0..47
  const int b = bh / 12, h = bh - b*12;
  const unsigned short* src = qkv + (size_t)(b*2048 + jt*64)*2304 + 1536 + h*64;
  #pragma unroll
  for(int c = t; c < 512; c += 256){
    int j = c >> 3, d0 = (c & 7) * 8;
    *(uint4*)&Ts[j*72 + d0] = *(const uint4*)(src + (size_t)j*2304 + d0);
  }
  __syncthreads();
  unsigned short* dst = VT + (size_t)bh*64*2048 + jt*64;
  #pragma unroll
  for(int c = t; c < 512; c += 256){
    int d = c >> 3, j0 = (c & 7) * 8;
    ushort4 lo, hi;
    lo.x = Ts[(j0+0)*72 + d]; lo.y = Ts[(j0+1)*72 + d];
    lo.z = Ts[(j0+2)*72 + d]; lo.w = Ts[(j0+3)*72 + d];
    hi.x = Ts[(j0+4)*72 + d]; hi.y = Ts[(j0+5)*72 + d];
    hi.z = Ts[(j0+6)*72 + d]; hi.w = Ts[(j0+7)*72 + d];
    *(ushort4*)(dst + (size_t)d*2048 + j0)     = lo;
    *(ushort4*)(dst + (size_t)d*2048 + j0 + 4) = hi;
  }
}

// ---------------------------------------------------------------------------
// MFMA GEMM-BT v2: C = A*Bt^T + bias. 128x128 tile, BK=32, DOUBLE-BUFFERED
// global_load_lds.
// ---------------------------------------------------------------------------
template<typename OT>
__global__ __launch_bounds__(256) void gemm_bt(const unsigned short* __restrict__ A,
                                               const unsigned short* __restrict__ Bt,
                                               const float* __restrict__ bias,
                                               OT* __restrict__ C,
                                               int M, int N, int K, int lda){
  __shared__ __align__(16) unsigned short As[2][128*32];
  __shared__ __align__(16) unsigned short Bs[2][128*32];
  const int tid  = threadIdx.x;
  const int lane = tid & 63, w = tid >> 6;
  const int m0 = blockIdx.y * 128, n0 = blockIdx.x * 128;

  f32x4 acc[4][4];
  #pragma unroll
  for(int i=0;i<4;i++)
    #pragma unroll
    for(int j=0;j<4;j++) acc[i][j] = (f32x4){0.f,0.f,0.f,0.f};

  const int c0 = w*64 + lane, c1 = c0 + 256;
  const unsigned short* Ag0 = A  + (size_t)(m0 + (c0>>2)) * lda + (c0&3)*8;
  const unsigned short* Ag1 = A  + (size_t)(m0 + (c1>>2)) * lda + (c1&3)*8;
  const unsigned short* Bg0 = Bt + (size_t)(n0 + (c0>>2)) * K   + (c0&3)*8;
  const unsigned short* Bg1 = Bt + (size_t)(n0 + (c1>>2)) * K   + (c1&3)*8;

  const int wm = w & 1, wn = w >> 1;
  const int quad = lane >> 4, l15 = lane & 15;

  // prologue: stage tile 0 into buffer 0
  GLD16(Ag0, As[0] +        w*512);
  GLD16(Ag1, As[0] + 2048 + w*512);
  GLD16(Bg0, Bs[0] +        w*512);
  GLD16(Bg1, Bs[0] + 2048 + w*512);

  int cur = 0;
  for(int kt = 0; kt < K; kt += 32){
    __syncthreads();               // drains GLD16(cur) for all waves
    if(kt + 32 < K){               // issue next tile into the other buffer
      int nx = cur ^ 1;
      GLD16(Ag0 + kt + 32, As[nx] +        w*512);
      GLD16(Ag1 + kt + 32, As[nx] + 2048 + w*512);
      GLD16(Bg0 + kt + 32, Bs[nx] +        w*512);
      GLD16(Bg1 + kt + 32, Bs[nx] + 2048 + w*512);
    }

    bf16x8 af[4], bfr[4];
    #pragma unroll
    for(int mt=0;mt<4;mt++) af[mt]  = *(const bf16x8*)&As[cur][(wm*64 + mt*16 + l15)*32 + quad*8];
    #pragma unroll
    for(int nt=0;nt<4;nt++) bfr[nt] = *(const bf16x8*)&Bs[cur][(wn*64 + nt*16 + l15)*32 + quad*8];
    #pragma unroll
    for(int mt=0;mt<4;mt++)
      #pragma unroll
      for(int nt=0;nt<4;nt++)
        acc[mt][nt] = __builtin_amdgcn_mfma_f32_16x16x32_bf16(af[mt], bfr[nt], acc[mt][nt], 0, 0, 0);
    cur ^= 1;
  }

  // epilogue: C/D layout col=lane&15, row=quad*4+reg
  #pragma unroll
  for(int nt=0;nt<4;nt++){
    int col = n0 + wn*64 + nt*16 + l15;
    float bv = bias[col];
    #pragma unroll
    for(int mt=0;mt<4;mt++){
      int row0 = m0 + wm*64 + mt*16 + quad*4;
      #pragma unroll
      for(int i=0;i<4;i++){
        float v = acc[mt][nt][i] + bv;
        if constexpr (sizeof(OT) == 2)
          C[(size_t)(row0 + i) * N + col] = (OT)fast2bf(v);
        else
          C[(size_t)(row0 + i) * N + col] = (OT)v;
      }
    }
  }
}

// ---------------------------------------------------------------------------
// MFMA flash attention v7 — wave-independent, in-register softmax.
//
// Block = 256 threads = 4 waves; wave w owns q-rows q0 = bx*128 + w*32.
// Grid (16,12,4) = 768 blocks = 3 blocks/CU exactly.
//
// Per 32-k KV step (32x32x16 MFMAs):
//   S^T = mfma(A=K[32k x 16d-chunk], B=Q[16d x 32q]) x4 d-chunks
//     -> D col = q = lane&31 (softmax row is LANE-LOCAL), row k=(r&3)+8(r>>2)+4hi
//   p = exp2(S) (Q pre-scaled by 0.125*log2e, fixed-zero max); l += p (scalar!)
//   P -> PV A-frags in-register: 8x v_cvt_pk_bf16_f32 + 4x permlane32_swap
//     chunk0 (k0..15) = swap(d0,d2), swap(d1,d3); chunk1 (k16..31) likewise.
//   O += mfma(A=P[32q x 16k], B=V[16k x 32d]) x2 k-chunks x2 d-blocks.
// No barriers in the main loop; no P LDS traffic; K prefetched 1 tile ahead.
// Epilogue: l across hi-halves via shfl_xor(32); 1/l broadcast via 128B LDS.
// ---------------------------------------------------------------------------
__global__ __launch_bounds__(256, 3) void attn_mfma(unsigned short* __restrict__ qkv,
                                                    const unsigned short* __restrict__ VT){
  __shared__ float linv_lds[4*32];

  const int t    = threadIdx.x;
  const int lane = t & 63, w = t >> 6;
  const int l31  = lane & 31, hi = lane >> 5;
  const int b = blockIdx.z, h = blockIdx.y;
  const int q0 = blockIdx.x * 128 + w * 32;

  unsigned short* Qg = qkv + (size_t)(b*2048 + q0)*2304 + h*64;

  // ---- Q B-frags: qf[c] = Q[q=l31][d = c*16 + hi*8 + 0..7], pre-scaled ----
  const float QSCALE = 0.125f * 1.4426950408889634f;
  bf16x8 qf[4];
  #pragma unroll
  for(int c=0;c<4;c++){
    uint4 raw = *(const uint4*)(Qg + (size_t)l31*2304 + c*16 + hi*8);
    const unsigned short* rp = (const unsigned short*)&raw;
    unsigned short o[8];
    #pragma unroll
    for(int e=0;e<8;e++) o[e] = fast2bf(bf2f(rp[e]) * QSCALE);
    qf[c] = *(const bf16x8*)o;
  }

  f32x16 oacc0, oacc1;
  #pragma unroll
  for(int i=0;i<16;i++){ oacc0[i] = 0.f; oacc1[i] = 0.f; }
  float lpart = 0.f;

  const size_t KSTEP = (size_t)32*2304;
  const unsigned short* Kp = qkv + (size_t)(b*2048)*2304 + 768 + h*64
                           + (size_t)l31*2304 + hi*8;
  const unsigned short* Vp = VT + (size_t)(b*12 + h)*64*2048
                           + (size_t)l31*2048 + hi*8;

  // prologue: K frags for tile 0 (kf[c] = K[k=l31][d = c*16 + hi*8 + 0..7])
  bf16x8 kf[4];
  #pragma unroll
  for(int c=0;c<4;c++) kf[c] = *(const bf16x8*)(Kp + c*16);

  #pragma unroll 1
  for(int kt = 0; kt < 2048; kt += 32){
    // ---- S^T tile: 32k x 32q ----
    f32x16 sacc;
    #pragma unroll
    for(int i=0;i<16;i++) sacc[i] = 0.f;
    sacc = __builtin_amdgcn_mfma_f32_32x32x16_bf16(kf[0], qf[0], sacc, 0, 0, 0);
    sacc = __builtin_amdgcn_mfma_f32_32x32x16_bf16(kf[1], qf[1], sacc, 0, 0, 0);
    sacc = __builtin_amdgcn_mfma_f32_32x32x16_bf16(kf[2], qf[2], sacc, 0, 0, 0);
    sacc = __builtin_amdgcn_mfma_f32_32x32x16_bf16(kf[3], qf[3], sacc, 0, 0, 0);

    // ---- V frags for this tile (issued early; latency hides under exp) ----
    bf16x8 vf00 = *(const bf16x8*)(Vp + kt);                        // k 0..15, d 0..31
    bf16x8 vf10 = *(const bf16x8*)(Vp + kt + 16);                   // k16..31, d 0..31
    bf16x8 vf01 = *(const bf16x8*)(Vp + kt + (size_t)32*2048);      // k 0..15, d32..63
    bf16x8 vf11 = *(const bf16x8*)(Vp + kt + (size_t)32*2048 + 16); // k16..31, d32..63

    // ---- prefetch next K tile ----
    if(kt + 32 < 2048){
      Kp += KSTEP;
      #pragma unroll
      for(int c=0;c<4;c++) kf[c] = *(const bf16x8*)(Kp + c*16);
    }

    // ---- softmax numerator: p = 2^sacc; lane-local row sum ----
    float p[16];
    #pragma unroll
    for(int r=0;r<16;r++){ p[r] = EXP2F(sacc[r]); lpart += p[r]; }

    // ---- P -> A-frags in-register ----
    // reg r holds k-row (r&3)+8*(r>>2)+4*hi; cvt_pk pairs adjacent k.
    unsigned int d0 = cvtpk_bf16(p[0],  p[1]);   // k = 4hi+0,1
    unsigned int d1 = cvtpk_bf16(p[2],  p[3]);   // k = 4hi+2,3
    unsigned int d2 = cvtpk_bf16(p[4],  p[5]);   // k = 8+4hi+0,1
    unsigned int d3 = cvtpk_bf16(p[6],  p[7]);   // k = 8+4hi+2,3
    unsigned int d4 = cvtpk_bf16(p[8],  p[9]);   // k = 16+4hi+0,1
    unsigned int d5 = cvtpk_bf16(p[10], p[11]);  // k = 16+4hi+2,3
    unsigned int d6 = cvtpk_bf16(p[12], p[13]);  // k = 24+4hi+0,1
    unsigned int d7 = cvtpk_bf16(p[14], p[15]);  // k = 24+4hi+2,3
    plswap32(d0, d2); plswap32(d1, d3);          // -> chunk0: k = 8hi + 0..7
    plswap32(d4, d6); plswap32(d5, d7);          // -> chunk1: k = 16 + 8hi + 0..7
    unsigned int c0w[4] = {d0, d1, d2, d3};
    unsigned int c1w[4] = {d4, d5, d6, d7};
    bf16x8 pa0 = *(const bf16x8*)c0w;            // P[q=l31][k = hi*8+0..7]
    bf16x8 pa1 = *(const bf16x8*)c1w;            // P[q=l31][k = 16+hi*8+0..7]

    // ---- PV: O[32q x 64d] accumulate ----
    oacc0 = __builtin_amdgcn_mfma_f32_32x32x16_bf16(pa0, vf00, oacc0, 0, 0, 0);
    oacc1 = __builtin_amdgcn_mfma_f32_32x32x16_bf16(pa0, vf01, oacc1, 0, 0, 0);
    oacc0 = __builtin_amdgcn_mfma_f32_32x32x16_bf16(pa1, vf10, oacc0, 0, 0, 0);
    oacc1 = __builtin_amdgcn_mfma_f32_32x32x16_bf16(pa1, vf11, oacc1, 0, 0, 0);
  }

  // ---- l: combine hi-halves (lane l and l^32 share q=l31), broadcast 1/l ----
  lpart += __shfl_xor(lpart, 32, 64);
  if(lane < 32) linv_lds[w*32 + l31] = 1.0f / lpart;
  __syncthreads();   // once per kernel; orders intra-wave LDS write->read too

  // ---- epilogue: O row q=(r&3)+8(r>>2)+4hi, col d = dblk*32 + l31 ----
  #pragma unroll
  for(int r=0;r<16;r++){
    int qrow = (r&3) + 8*(r>>2) + 4*hi;
    float li = linv_lds[w*32 + qrow];
    unsigned short* row = Qg + (size_t)qrow*2304;
    row[l31]      = fast2bf(oacc0[r] * li);
    row[32 + l31] = fast2bf(oacc1[r] * li);
  }
}

// ---------------------------------------------------------------------------
extern "C" void kernel_launch(void* const* d_in, const int* in_sizes, int n_in,
                              void* d_out, int out_size, void* d_ws, size_t ws_size,
                              hipStream_t stream){
  const float* x      = (const float*)d_in[0];  // [8192][768]
  const float* w_qkv  = (const float*)d_in[1];  // [768][2304]
  const float* b_qkv  = (const float*)d_in[2];  // [2304]
  const float* w_proj = (const float*)d_in[3];  // [768][768]
  const float* b_proj = (const float*)d_in[4];  // [768]
  float* out = (float*)d_out;                   // [8192][768]

  unsigned short* xb      = (unsigned short*)d_ws;                   // [8192][768]
  unsigned short* Wt_qkv  = xb      + (size_t)8192*768;              // [2304][768]
  unsigned short* Wt_proj = Wt_qkv  + (size_t)2304*768;              // [768][768]
  unsigned short* qkvb    = Wt_proj + (size_t)768*768;               // [8192][2304]
  unsigned short* VT      = xb;   // aliases xb: xb dead after gemm1

  f32_to_bf16<<<(8192*768)/1024, 256, 0, stream>>>(x, xb, 8192*768);
  transpose_f32_bf16<<<dim3(72, 24), dim3(32, 8), 0, stream>>>(w_qkv,  Wt_qkv,  768, 2304);
  transpose_f32_bf16<<<dim3(24, 24), dim3(32, 8), 0, stream>>>(w_proj, Wt_proj, 768, 768);

  gemm_bt<unsigned short><<<dim3(2304/128, 8192/128), 256, 0, stream>>>(
      xb, Wt_qkv, b_qkv, qkvb, 8192, 2304, 768, 768);

  transpose_v<<<dim3(32, 48), 256, 0, stream>>>(qkvb, VT);

  attn_mfma<<<dim3(2048/128, 12, 4), 256, 0, stream>>>(qkvb, VT);

  gemm_bt<float><<<dim3(768/128, 8192/128), 256, 0, stream>>>(
      qkvb, Wt_proj, b_proj, out, 8192, 768, 768, 2304);
}

// Round 2
// 217.472 us; speedup vs baseline: 1.5432x; 1.5432x over previous
//
#include <hip/hip_runtime.h>
#include <stdint.h>
#include <stddef.h>

// ---------------------------------------------------------------------------
// B=4, N=2048, D=768, H=12, HD=64. BN=8192.
// I/O fp32; internal bf16 MFMA + fp32 accum.
// qkv hidden [8192][2304] bf16 (Q 0..767 | K 768..1535 | V 1536..2303).
// V also materialized transposed: VT[(b*12+h)*64+d][2048 j] (aliases xb).
// Attention overwrites the Q region in place with merged-head output.
// attn v8: v7's verified in-register softmax (swapped 32x32x16 QK^T,
// cvt_pk_bf16 + permlane32_swap P-frags) + LDS-shared K/V tiles:
// 64-k double-buffered tiles staged via coalesced global_load_lds with
// XOR-swizzled source (chunk ^= row&7), conflict-free swizzled ds_read_b128
// frag loads, one barrier per tile. XCD-clustered block remap.
// ---------------------------------------------------------------------------

typedef __bf16 bf16x8 __attribute__((ext_vector_type(8)));
typedef float  f32x4  __attribute__((ext_vector_type(4)));
typedef float  f32x16 __attribute__((ext_vector_type(16)));
typedef unsigned int u32x2 __attribute__((ext_vector_type(2)));

__device__ __forceinline__ float bf2f(unsigned short u){
  union { unsigned int i; float f; } x; x.i = ((unsigned int)u) << 16; return x.f;
}
// round-half-up bf16
__device__ __forceinline__ unsigned short fast2bf(float f){
  union { float f; unsigned int i; } x; x.f = f;
  return (unsigned short)((x.i + 0x8000u) >> 16);
}
__device__ __forceinline__ unsigned int fbits(float f){
  union { float f; unsigned int i; } x; x.f = f; return x.i;
}
// single-instruction packed fp32->bf16 pair (RNE)
__device__ __forceinline__ unsigned int cvtpk_bf16(float lo, float hi){
  unsigned int r;
  asm("v_cvt_pk_bf16_f32 %0, %1, %2" : "=v"(r) : "v"(lo), "v"(hi));
  return r;
}
// v_permlane32_swap_b32: a' = {a.lo32lanes, b.lo32lanes}, b' = {a.hi, b.hi}
__device__ __forceinline__ void plswap32(unsigned int &a, unsigned int &b){
#if __has_builtin(__builtin_amdgcn_permlane32_swap)
  u32x2 r = __builtin_amdgcn_permlane32_swap(a, b, false, false);
  a = r.x; b = r.y;
#else
  asm volatile("v_permlane32_swap_b32 %0, %1" : "+v"(a), "+v"(b));
#endif
}

#if __has_builtin(__builtin_amdgcn_exp2f)
  #define EXP2F(x) __builtin_amdgcn_exp2f(x)
#else
  #define EXP2F(x) exp2f(x)
#endif

// async global->LDS, 16B per lane; LDS dest = wave-uniform base + lane*16.
#define GLD16(gp, lp) __builtin_amdgcn_global_load_lds( \
  (__attribute__((address_space(1))) void*)(uintptr_t)(gp), \
  (__attribute__((address_space(3))) void*)(unsigned int)(uintptr_t)(lp), 16, 0, 0)

// ---------------------------------------------------------------------------
__global__ void f32_to_bf16(const float* __restrict__ in,
                            unsigned short* __restrict__ out, int n){
  int i = (blockIdx.x * 256 + threadIdx.x) * 4;
  if(i < n){
    float4 v = *(const float4*)(in + i);
    ushort4 o;
    o.x = fast2bf(v.x); o.y = fast2bf(v.y); o.z = fast2bf(v.z); o.w = fast2bf(v.w);
    *(ushort4*)(out + i) = o;
  }
}

// ---------------------------------------------------------------------------
__global__ void transpose_f32_bf16(const float* __restrict__ W,
                                   unsigned short* __restrict__ Wt, int K, int N){
  __shared__ float tile[32][33];
  int n0 = blockIdx.x * 32, k0 = blockIdx.y * 32;
  int tx = threadIdx.x, ty = threadIdx.y;   // (32,8)
  for(int i = ty; i < 32; i += 8) tile[i][tx] = W[(size_t)(k0 + i) * N + (n0 + tx)];
  __syncthreads();
  for(int i = ty; i < 32; i += 8) Wt[(size_t)(n0 + i) * K + (k0 + tx)] = fast2bf(tile[tx][i]);
}

// ---------------------------------------------------------------------------
// V transpose: VT[(b*12+h)*64 + d][j] = qkv[b*2048+j][1536 + h*64 + d]
// ---------------------------------------------------------------------------
__global__ __launch_bounds__(256) void transpose_v(const unsigned short* __restrict__ qkv,
                                                   unsigned short* __restrict__ VT){
  __shared__ __align__(16) unsigned short Ts[64*72];
  const int t  = threadIdx.x;
  const int jt = blockIdx.x;        // 0..31
  const int bh = blockIdx.y;        // 0..47
  const int b = bh / 12, h = bh - b*12;
  const unsigned short* src = qkv + (size_t)(b*2048 + jt*64)*2304 + 1536 + h*64;
  #pragma unroll
  for(int c = t; c < 512; c += 256){
    int j = c >> 3, d0 = (c & 7) * 8;
    *(uint4*)&Ts[j*72 + d0] = *(const uint4*)(src + (size_t)j*2304 + d0);
  }
  __syncthreads();
  unsigned short* dst = VT + (size_t)bh*64*2048 + jt*64;
  #pragma unroll
  for(int c = t; c < 512; c += 256){
    int d = c >> 3, j0 = (c & 7) * 8;
    ushort4 lo, hi;
    lo.x = Ts[(j0+0)*72 + d]; lo.y = Ts[(j0+1)*72 + d];
    lo.z = Ts[(j0+2)*72 + d]; lo.w = Ts[(j0+3)*72 + d];
    hi.x = Ts[(j0+4)*72 + d]; hi.y = Ts[(j0+5)*72 + d];
    hi.z = Ts[(j0+6)*72 + d]; hi.w = Ts[(j0+7)*72 + d];
    *(ushort4*)(dst + (size_t)d*2048 + j0)     = lo;
    *(ushort4*)(dst + (size_t)d*2048 + j0 + 4) = hi;
  }
}

// ---------------------------------------------------------------------------
// MFMA GEMM-BT v2: C = A*Bt^T + bias. 128x128 tile, BK=32, DOUBLE-BUFFERED
// global_load_lds.
// ---------------------------------------------------------------------------
template<typename OT>
__global__ __launch_bounds__(256) void gemm_bt(const unsigned short* __restrict__ A,
                                               const unsigned short* __restrict__ Bt,
                                               const float* __restrict__ bias,
                                               OT* __restrict__ C,
                                               int M, int N, int K, int lda){
  __shared__ __align__(16) unsigned short As[2][128*32];
  __shared__ __align__(16) unsigned short Bs[2][128*32];
  const int tid  = threadIdx.x;
  const int lane = tid & 63, w = tid >> 6;
  const int m0 = blockIdx.y * 128, n0 = blockIdx.x * 128;

  f32x4 acc[4][4];
  #pragma unroll
  for(int i=0;i<4;i++)
    #pragma unroll
    for(int j=0;j<4;j++) acc[i][j] = (f32x4){0.f,0.f,0.f,0.f};

  const int c0 = w*64 + lane, c1 = c0 + 256;
  const unsigned short* Ag0 = A  + (size_t)(m0 + (c0>>2)) * lda + (c0&3)*8;
  const unsigned short* Ag1 = A  + (size_t)(m0 + (c1>>2)) * lda + (c1&3)*8;
  const unsigned short* Bg0 = Bt + (size_t)(n0 + (c0>>2)) * K   + (c0&3)*8;
  const unsigned short* Bg1 = Bt + (size_t)(n0 + (c1>>2)) * K   + (c1&3)*8;

  const int wm = w & 1, wn = w >> 1;
  const int quad = lane >> 4, l15 = lane & 15;

  // prologue: stage tile 0 into buffer 0
  GLD16(Ag0, As[0] +        w*512);
  GLD16(Ag1, As[0] + 2048 + w*512);
  GLD16(Bg0, Bs[0] +        w*512);
  GLD16(Bg1, Bs[0] + 2048 + w*512);

  int cur = 0;
  for(int kt = 0; kt < K; kt += 32){
    __syncthreads();               // drains GLD16(cur) for all waves
    if(kt + 32 < K){               // issue next tile into the other buffer
      int nx = cur ^ 1;
      GLD16(Ag0 + kt + 32, As[nx] +        w*512);
      GLD16(Ag1 + kt + 32, As[nx] + 2048 + w*512);
      GLD16(Bg0 + kt + 32, Bs[nx] +        w*512);
      GLD16(Bg1 + kt + 32, Bs[nx] + 2048 + w*512);
    }

    bf16x8 af[4], bfr[4];
    #pragma unroll
    for(int mt=0;mt<4;mt++) af[mt]  = *(const bf16x8*)&As[cur][(wm*64 + mt*16 + l15)*32 + quad*8];
    #pragma unroll
    for(int nt=0;nt<4;nt++) bfr[nt] = *(const bf16x8*)&Bs[cur][(wn*64 + nt*16 + l15)*32 + quad*8];
    #pragma unroll
    for(int mt=0;mt<4;mt++)
      #pragma unroll
      for(int nt=0;nt<4;nt++)
        acc[mt][nt] = __builtin_amdgcn_mfma_f32_16x16x32_bf16(af[mt], bfr[nt], acc[mt][nt], 0, 0, 0);
    cur ^= 1;
  }

  // epilogue: C/D layout col=lane&15, row=quad*4+reg
  #pragma unroll
  for(int nt=0;nt<4;nt++){
    int col = n0 + wn*64 + nt*16 + l15;
    float bv = bias[col];
    #pragma unroll
    for(int mt=0;mt<4;mt++){
      int row0 = m0 + wm*64 + mt*16 + quad*4;
      #pragma unroll
      for(int i=0;i<4;i++){
        float v = acc[mt][nt][i] + bv;
        if constexpr (sizeof(OT) == 2)
          C[(size_t)(row0 + i) * N + col] = (OT)fast2bf(v);
        else
          C[(size_t)(row0 + i) * N + col] = (OT)v;
      }
    }
  }
}

// ---------------------------------------------------------------------------
// MFMA flash attention v8 — wave-independent softmax, LDS-shared K/V tiles.
//
// Block = 256 threads = 4 waves; wave w owns q-rows q0 = bx*128 + w*32.
// 1-D grid 768 blocks, XCD-clustered remap (blocks sharing (b,h) -> same XCD).
//
// K/V staged per 64-k tile into LDS (double-buffered, 32 KB):
//   tile row = k (K) or d (V), 64 rows x 128B. Stage via GLD16, 2 rounds per
//   wave per matrix (w*8+lane>>3 rows), SOURCE chunk pre-swizzled by
//   (lane&7)^(lane>>3)  ->  LDS[row][c] = M[row][c ^ (row&7)].
//   Frag ds_read_b128 at chunk (cc ^ (l31&7)): 8 lanes per 4-bank group,
//   distinct rows -> conflict-free (8-cycle wave read).
// Per 32-k step (32x32x16 MFMAs, verified v7 math):
//   S^T = mfma(A=K,B=Q) -> q = lane&31 lane-local; p=exp2; l += p (scalar);
//   P-frags via 8x cvt_pk_bf16 + 4x permlane32_swap; O += mfma(P,V) x4.
// One barrier per 64-k tile (drains next-tile GLD16, proven gemm_bt pattern).
// ---------------------------------------------------------------------------
__global__ __launch_bounds__(256, 3) void attn_mfma(unsigned short* __restrict__ qkv,
                                                    const unsigned short* __restrict__ VT){
  __shared__ __align__(16) unsigned short Ks[2][64*64];
  __shared__ __align__(16) unsigned short Vs[2][64*64];
  __shared__ float linv_lds[4*32];

  const int t    = threadIdx.x;
  const int lane = t & 63, w = t >> 6;
  const int l31  = lane & 31, hi = lane >> 5;
  const int sx   = l31 & 7;            // ds_read swizzle key (row&7)

  // XCD-clustered bijective remap: hw-consecutive ids on one XCD get a
  // contiguous logical range -> the 16 blocks sharing (b,h) share one L2.
  const int bid = blockIdx.x;                 // 0..767, 768 % 8 == 0
  const int wg  = (bid & 7) * 96 + (bid >> 3);
  const int b   = wg / 192;                   // 16*12 = 192
  const int rem = wg - b * 192;
  const int h   = rem >> 4;
  const int bx  = rem & 15;
  const int q0  = bx * 128 + w * 32;

  unsigned short* Qg = qkv + (size_t)(b*2048 + q0)*2304 + h*64;

  // ---- Q B-frags: qf[c] = Q[q=l31][d = c*16 + hi*8 + 0..7], pre-scaled ----
  const float QSCALE = 0.125f * 1.4426950408889634f;
  bf16x8 qf[4];
  #pragma unroll
  for(int c=0;c<4;c++){
    uint4 raw = *(const uint4*)(Qg + (size_t)l31*2304 + c*16 + hi*8);
    const unsigned short* rp = (const unsigned short*)&raw;
    unsigned short o[8];
    #pragma unroll
    for(int e=0;e<8;e++) o[e] = fast2bf(bf2f(rp[e]) * QSCALE);
    qf[c] = *(const bf16x8*)o;
  }

  f32x16 oacc0, oacc1;
  #pragma unroll
  for(int i=0;i<16;i++){ oacc0[i] = 0.f; oacc1[i] = 0.f; }
  float lpart = 0.f;

  // ---- staging geometry: 2 GLD16 rounds/wave/matrix, rows w*8+(lane>>3) ----
  const int r8 = lane >> 3, c8 = lane & 7;
  const int scw = c8 ^ r8;                    // source chunk (row&7 == r8)
  const unsigned short* gK = qkv + (size_t)(b*2048)*2304 + 768 + h*64;   // +kt*2304
  const unsigned short* gV = VT + (size_t)(b*12 + h)*64*2048;            // +kt
  const size_t kOffA = (size_t)(w*8 + r8)*2304 + scw*8;
  const size_t kOffB = kOffA + (size_t)32*2304;
  const size_t vOffA = (size_t)(w*8 + r8)*2048 + scw*8;
  const size_t vOffB = vOffA + (size_t)32*2048;

  // prologue: stage tile 0 into buffer 0
  GLD16(gK + kOffA, Ks[0] +        w*512);
  GLD16(gK + kOffB, Ks[0] + 2048 + w*512);
  GLD16(gV + vOffA, Vs[0] +        w*512);
  GLD16(gV + vOffB, Vs[0] + 2048 + w*512);

  int cur = 0;
  #pragma unroll 1
  for(int it = 0; it < 32; ++it){
    __syncthreads();               // buf[cur] staged (drains GLD16) for all waves
    if(it + 1 < 32){               // stage next 64-k tile into other buffer
      int nx = cur ^ 1;
      gK += (size_t)64*2304;
      gV += 64;
      GLD16(gK + kOffA, Ks[nx] +        w*512);
      GLD16(gK + kOffB, Ks[nx] + 2048 + w*512);
      GLD16(gV + vOffA, Vs[nx] +        w*512);
      GLD16(gV + vOffB, Vs[nx] + 2048 + w*512);
    }
    const unsigned short* Kst = Ks[cur];
    const unsigned short* Vst = Vs[cur];

    #pragma unroll
    for(int ks = 0; ks < 2; ++ks){
      // ---- K frags: kf[c] = K[k = ks*32 + l31][d = c*16 + hi*8 + 0..7] ----
      bf16x8 kf[4];
      #pragma unroll
      for(int c=0;c<4;c++)
        kf[c] = *(const bf16x8*)&Kst[(ks*32 + l31)*64 + (((c*2 + hi) ^ sx) * 8)];

      // ---- S^T tile: 32k x 32q ----
      f32x16 sacc;
      #pragma unroll
      for(int i=0;i<16;i++) sacc[i] = 0.f;
      sacc = __builtin_amdgcn_mfma_f32_32x32x16_bf16(kf[0], qf[0], sacc, 0, 0, 0);
      sacc = __builtin_amdgcn_mfma_f32_32x32x16_bf16(kf[1], qf[1], sacc, 0, 0, 0);
      sacc = __builtin_amdgcn_mfma_f32_32x32x16_bf16(kf[2], qf[2], sacc, 0, 0, 0);
      sacc = __builtin_amdgcn_mfma_f32_32x32x16_bf16(kf[3], qf[3], sacc, 0, 0, 0);

      // ---- V frags (issued before exp; lgkm latency hides under VALU) ----
      // vf(khalf,dblk): V[k = ks*32 + khalf*16 + hi*8 + e][d = dblk*32 + l31]
      bf16x8 vf00 = *(const bf16x8*)&Vst[(     l31)*64 + (((ks*4 + 0 + hi) ^ sx) * 8)];
      bf16x8 vf01 = *(const bf16x8*)&Vst[(32 + l31)*64 + (((ks*4 + 0 + hi) ^ sx) * 8)];
      bf16x8 vf10 = *(const bf16x8*)&Vst[(     l31)*64 + (((ks*4 + 2 + hi) ^ sx) * 8)];
      bf16x8 vf11 = *(const bf16x8*)&Vst[(32 + l31)*64 + (((ks*4 + 2 + hi) ^ sx) * 8)];

      // ---- softmax numerator: p = 2^sacc; lane-local row sum ----
      float p[16];
      #pragma unroll
      for(int r=0;r<16;r++){ p[r] = EXP2F(sacc[r]); lpart += p[r]; }

      // ---- P -> A-frags in-register (verified v7 pipeline) ----
      unsigned int d0 = cvtpk_bf16(p[0],  p[1]);
      unsigned int d1 = cvtpk_bf16(p[2],  p[3]);
      unsigned int d2 = cvtpk_bf16(p[4],  p[5]);
      unsigned int d3 = cvtpk_bf16(p[6],  p[7]);
      unsigned int d4 = cvtpk_bf16(p[8],  p[9]);
      unsigned int d5 = cvtpk_bf16(p[10], p[11]);
      unsigned int d6 = cvtpk_bf16(p[12], p[13]);
      unsigned int d7 = cvtpk_bf16(p[14], p[15]);
      plswap32(d0, d2); plswap32(d1, d3);          // chunk0: k = 8hi + 0..7
      plswap32(d4, d6); plswap32(d5, d7);          // chunk1: k = 16 + 8hi + 0..7
      unsigned int c0w[4] = {d0, d1, d2, d3};
      unsigned int c1w[4] = {d4, d5, d6, d7};
      bf16x8 pa0 = *(const bf16x8*)c0w;            // P[q=l31][k = hi*8+0..7]
      bf16x8 pa1 = *(const bf16x8*)c1w;            // P[q=l31][k = 16+hi*8+0..7]

      // ---- PV: O[32q x 64d] accumulate ----
      oacc0 = __builtin_amdgcn_mfma_f32_32x32x16_bf16(pa0, vf00, oacc0, 0, 0, 0);
      oacc1 = __builtin_amdgcn_mfma_f32_32x32x16_bf16(pa0, vf01, oacc1, 0, 0, 0);
      oacc0 = __builtin_amdgcn_mfma_f32_32x32x16_bf16(pa1, vf10, oacc0, 0, 0, 0);
      oacc1 = __builtin_amdgcn_mfma_f32_32x32x16_bf16(pa1, vf11, oacc1, 0, 0, 0);
    }
    cur ^= 1;
  }

  // ---- l: combine hi-halves (lane l and l^32 share q=l31), broadcast 1/l ----
  lpart += __shfl_xor(lpart, 32, 64);
  if(lane < 32) linv_lds[w*32 + l31] = 1.0f / lpart;
  __syncthreads();

  // ---- epilogue: O row q=(r&3)+8(r>>2)+4hi, col d = dblk*32 + l31 ----
  #pragma unroll
  for(int r=0;r<16;r++){
    int qrow = (r&3) + 8*(r>>2) + 4*hi;
    float li = linv_lds[w*32 + qrow];
    unsigned short* row = Qg + (size_t)qrow*2304;
    row[l31]      = fast2bf(oacc0[r] * li);
    row[32 + l31] = fast2bf(oacc1[r] * li);
  }
}

// ---------------------------------------------------------------------------
extern "C" void kernel_launch(void* const* d_in, const int* in_sizes, int n_in,
                              void* d_out, int out_size, void* d_ws, size_t ws_size,
                              hipStream_t stream){
  const float* x      = (const float*)d_in[0];  // [8192][768]
  const float* w_qkv  = (const float*)d_in[1];  // [768][2304]
  const float* b_qkv  = (const float*)d_in[2];  // [2304]
  const float* w_proj = (const float*)d_in[3];  // [768][768]
  const float* b_proj = (const float*)d_in[4];  // [768]
  float* out = (float*)d_out;                   // [8192][768]

  unsigned short* xb      = (unsigned short*)d_ws;                   // [8192][768]
  unsigned short* Wt_qkv  = xb      + (size_t)8192*768;              // [2304][768]
  unsigned short* Wt_proj = Wt_qkv  + (size_t)2304*768;              // [768][768]
  unsigned short* qkvb    = Wt_proj + (size_t)768*768;               // [8192][2304]
  unsigned short* VT      = xb;   // aliases xb: xb dead after gemm1

  f32_to_bf16<<<(8192*768)/1024, 256, 0, stream>>>(x, xb, 8192*768);
  transpose_f32_bf16<<<dim3(72, 24), dim3(32, 8), 0, stream>>>(w_qkv,  Wt_qkv,  768, 2304);
  transpose_f32_bf16<<<dim3(24, 24), dim3(32, 8), 0, stream>>>(w_proj, Wt_proj, 768, 768);

  gemm_bt<unsigned short><<<dim3(2304/128, 8192/128), 256, 0, stream>>>(
      xb, Wt_qkv, b_qkv, qkvb, 8192, 2304, 768, 768);

  transpose_v<<<dim3(32, 48), 256, 0, stream>>>(qkvb, VT);

  attn_mfma<<<768, 256, 0, stream>>>(qkvb, VT);

  gemm_bt<float><<<dim3(768/128, 8192/128), 256, 0, stream>>>(
      qkvb, Wt_proj, b_proj, out, 8192, 768, 768, 2304);
}